// Round 14
// baseline (312.340 us; speedup 1.0000x reference)
//
#include <hip/hip_runtime.h>
#include <math.h>

#define N_NODES 50000
#define N_EDGES 100000
#define FNODE 22
#define HDIM 64
#define BN_EPS 1e-5f

typedef __attribute__((ext_vector_type(8))) short bfrag;   // 8 bf16 = A/B operand
typedef __attribute__((ext_vector_type(4))) float facc;    // 4 f32  = C/D
typedef __attribute__((ext_vector_type(4))) unsigned int uint4v;

__device__ __forceinline__ unsigned f2bf(float x) {  // RNE f32->bf16
    unsigned u = __float_as_uint(x);
    return (u + 0x7FFFu + ((u >> 16) & 1u)) >> 16;
}
__device__ __forceinline__ unsigned pk2bf(float lo, float hi) {
    return f2bf(lo) | (f2bf(hi) << 16);
}

// ---------- CSR build (int atomics only; graph constant per call) ----------
__global__ void k_count(const int* __restrict__ eidx, int* __restrict__ cnt) {
    int e = blockIdx.x * 256 + threadIdx.x;
    if (e < N_EDGES) atomicAdd(&cnt[eidx[N_EDGES + e]], 1);
}

__global__ void k_scan(const int* __restrict__ cnt, int* __restrict__ base,
                       int* __restrict__ cursor) {
    __shared__ int part[1024];
    int t = threadIdx.x;
    const int PER = (N_NODES + 1023) / 1024;  // 49
    int beg = t * PER;
    int end = min(beg + PER, N_NODES);
    int s = 0;
    for (int i = beg; i < end; ++i) s += cnt[i];
    part[t] = s;
    __syncthreads();
    for (int off = 1; off < 1024; off <<= 1) {
        int v = part[t];
        int u = (t >= off) ? part[t - off] : 0;
        __syncthreads();
        part[t] = v + u;
        __syncthreads();
    }
    int run = (t == 0) ? 0 : part[t - 1];
    for (int i = beg; i < end; ++i) {
        base[i] = run;
        cursor[i] = run;
        run += cnt[i];
    }
    if (t == 1023) base[N_NODES] = part[1023];
}

__global__ void k_scatter(const int* __restrict__ eidx, int* __restrict__ cursor,
                          int* __restrict__ csr) {
    int e = blockIdx.x * 256 + threadIdx.x;
    if (e < N_EDGES) {
        int p = atomicAdd(&cursor[eidx[N_EDGES + e]], 1);
        csr[p] = e;
    }
}

// Gather-reduce: hout[n] = basebuf[n] + sum_{k in [base[n],base[n+1])} msg[csr[k]]
// (in-place basebuf==hout is safe: wave reads its row before writing it)
__global__ void k_reduce(const float* __restrict__ basebuf, const float* __restrict__ msg,
                         const int* __restrict__ base, const int* __restrict__ csr,
                         float* __restrict__ hout) {
    int lane = threadIdx.x & 63;
    int n = blockIdx.x * 4 + (threadIdx.x >> 6);
    if (n >= N_NODES) return;
    float acc = basebuf[(size_t)n * HDIM + lane];
    int b = base[n], e = base[n + 1];
    for (int k = b; k < e; ++k)
        acc += msg[(size_t)csr[k] * HDIM + lane];
    hout[(size_t)n * HDIM + lane] = acc;
}

// ---------- weight packing ----------
template <int K>
__global__ void k_packB(const float* __restrict__ W, uint4v* __restrict__ Bt) {
    constexpr int NQ = (K + 31) / 32;
    int t = threadIdx.x;
    int ot = t >> 6, lane = t & 63;
    int o = ot * 16 + (lane & 15);
    int kg = lane >> 4;
#pragma unroll
    for (int q = 0; q < NQ; ++q) {
        unsigned w[4];
#pragma unroll
        for (int p = 0; p < 4; ++p) {
            int k0 = q * 32 + kg * 8 + 2 * p;
            float lo = (k0 < K) ? W[k0 * HDIM + o] : 0.f;
            float hi = (k0 + 1 < K) ? W[(k0 + 1) * HDIM + o] : 0.f;
            w[p] = pk2bf(lo, hi);
        }
        Bt[(ot * NQ + q) * 64 + lane] = uint4v{w[0], w[1], w[2], w[3]};
    }
}

// MFMA node1: hroot1 = b1 + x @ root1
__global__ void k_node1(const float* __restrict__ x, const uint4v* __restrict__ Bt1,
                        const float* __restrict__ b1, float* __restrict__ h1) {
    int lane = threadIdx.x & 63;
    int m = lane & 15, kg = lane >> 4, orow4 = kg * 4;
    int tile = blockIdx.x * 4 + (threadIdx.x >> 6);
    int nb = tile * 16;
    if (nb >= N_NODES) return;
    const float* xr = x + (size_t)(nb + m) * FNODE;
    float xv[8];
#pragma unroll
    for (int p = 0; p < 4; ++p) {
        int c = kg * 8 + 2 * p;
        float2 v = (c + 1 < FNODE) ? *(const float2*)(xr + c) : float2{0.f, 0.f};
        xv[2 * p] = v.x; xv[2 * p + 1] = v.y;
    }
    bfrag A = __builtin_bit_cast(bfrag, uint4v{pk2bf(xv[0], xv[1]), pk2bf(xv[2], xv[3]),
                                               pk2bf(xv[4], xv[5]), pk2bf(xv[6], xv[7])});
    const facc zero4 = {0.f, 0.f, 0.f, 0.f};
#pragma unroll
    for (int ot = 0; ot < 4; ++ot) {
        bfrag B = __builtin_bit_cast(bfrag, Bt1[ot * 64 + lane]);
        facc d = __builtin_amdgcn_mfma_f32_16x16x32_bf16(A, B, zero4, 0, 0, 0);
        float bv = b1[ot * 16 + m];
#pragma unroll
        for (int j = 0; j < 4; ++j)
            h1[(size_t)(nb + orow4 + j) * HDIM + ot * 16 + m] = d[j] + bv;
    }
}

// MFMA edge kernel v10: IDENTICAL compute to R13 (16 edges/wave, o-split pairs, 20KB LDS,
// i-pair weights, bias via MFMA C-operand) but stores messages DENSELY edge-major
// (plain coalesced full-line stores) instead of device-scope FP atomics (the R13-diagnosed
// MALL atomic-sink bottleneck). dst-index loads are gone (CSR reduce handles the gather).
template <int IN, int CHUNK>
__launch_bounds__(256, 6)
__global__ void k_edge(const float* __restrict__ h, const float* __restrict__ ea,
                       const float* __restrict__ We, const float* __restrict__ be,
                       const int* __restrict__ eidx, float* __restrict__ msg) {
    constexpr int INH = IN * HDIM;
    constexpr int IP = IN / 2;
    __shared__ uint4v Wd[IP * 32];
    __shared__ unsigned Bp[IP * 32];

    int obeg = (blockIdx.x & 1) * 32;
    int tileblk = blockIdx.x >> 1;

    for (int idx = threadIdx.x; idx < IP * 32; idx += 256) {
        int ip = idx >> 5, oloc = idx & 31;
        int c0 = (2 * ip) * HDIM + obeg + oloc;
        int c1 = c0 + HDIM;
        Wd[idx] = uint4v{pk2bf(We[c0], We[INH + c0]),
                         pk2bf(We[2 * INH + c0], We[3 * INH + c0]),
                         pk2bf(We[c1], We[INH + c1]),
                         pk2bf(We[2 * INH + c1], We[3 * INH + c1])};
        Bp[idx] = pk2bf(be[c0], be[c1]);
    }
    __syncthreads();

    int lane = threadIdx.x & 63;
    int e16 = lane & 15;
    int orow4 = (lane >> 4) * 4;
    int tile = tileblk * 4 + (threadIdx.x >> 6);
    int ebase = tile * 16;
    if (ebase >= N_EDGES) return;

    bool act = lane < 16;
    float4 ea0 = ((const float4*)ea)[ebase + e16];
    bfrag A0 = __builtin_bit_cast(bfrag, uint4v{act ? pk2bf(ea0.x, ea0.y) : 0u,
                                                act ? pk2bf(ea0.z, ea0.w) : 0u, 0u, 0u});

    const char* hb = (const char*)h;
    unsigned offA[4];
#pragma unroll
    for (int j = 0; j < 4; ++j)
        offA[j] = (unsigned)eidx[ebase + orow4 + j] * (IN * 4);

    const facc zero4 = {0.f, 0.f, 0.f, 0.f};
    facc m0[2] = {zero4, zero4};

#pragma unroll
    for (int i0 = 0; i0 < IN; i0 += CHUNK) {
        float cA[4][CHUNK];
#pragma unroll
        for (int j = 0; j < 4; ++j) {
            if constexpr (CHUNK == 4) {
                float4 v = *(const float4*)(hb + offA[j] + (size_t)i0 * 4);
                cA[j][0] = v.x; cA[j][1] = v.y; cA[j][2] = v.z; cA[j][3] = v.w;
            } else {
                float2 v = *(const float2*)(hb + offA[j] + (size_t)i0 * 4);
                cA[j][0] = v.x; cA[j][1] = v.y;
            }
        }
#pragma unroll
        for (int t = 0; t < 2; ++t) {
#pragma unroll
            for (int d2 = 0; d2 < CHUNK / 2; ++d2) {
                int ip = i0 / 2 + d2;
                uint4v wq = Wd[ip * 32 + t * 16 + e16];
                unsigned bq = Bp[ip * 32 + t * 16 + e16];
                float bl = __uint_as_float(bq << 16);
                float bh = __uint_as_float(bq & 0xFFFF0000u);
                facc cl = {bl, bl, bl, bl};
                facc ch = {bh, bh, bh, bh};
                bfrag Blo = __builtin_bit_cast(bfrag, uint4v{wq.x, wq.y, 0u, 0u});
                bfrag Bhi = __builtin_bit_cast(bfrag, uint4v{wq.z, wq.w, 0u, 0u});
                facc t0 = __builtin_amdgcn_mfma_f32_16x16x32_bf16(A0, Blo, cl, 0, 0, 0);
#pragma unroll
                for (int j = 0; j < 4; ++j)
                    m0[t][j] = fmaf(cA[j][2 * d2], fmaxf(t0[j], 0.f), m0[t][j]);
                t0 = __builtin_amdgcn_mfma_f32_16x16x32_bf16(A0, Bhi, ch, 0, 0, 0);
#pragma unroll
                for (int j = 0; j < 4; ++j)
                    m0[t][j] = fmaf(cA[j][2 * d2 + 1], fmaxf(t0[j], 0.f), m0[t][j]);
            }
        }
    }

    // epilogue: dense edge-major stores; each instr = 4 edges x 16 contiguous dwords
    // (full 64B lines, o-half columns disjoint, no RMW)
#pragma unroll
    for (int t = 0; t < 2; ++t) {
#pragma unroll
        for (int j = 0; j < 4; ++j)
            msg[(size_t)(ebase + orow4 + j) * HDIM + obeg + t * 16 + e16] = m0[t][j];
    }
}

// Per-channel sum & sumsq over N rows -> stats[0:64]=sum, stats[64:128]=sumsq (pre-zeroed)
__global__ void k_stats(const float* __restrict__ hbuf, float* stats) {
    int c = threadIdx.x & 63;
    int r = threadIdx.x >> 6;
    int rowsPer = blockDim.x >> 6;
    float s = 0.f, q = 0.f;
    for (int n = blockIdx.x * rowsPer + r; n < N_NODES; n += gridDim.x * rowsPer) {
        float v = hbuf[n * HDIM + c];
        s += v;
        q = fmaf(v, v, q);
    }
    __shared__ float ls[4][64], lq[4][64];
    ls[r][c] = s;
    lq[r][c] = q;
    __syncthreads();
    if (r == 0) {
        s = ls[0][c] + ls[1][c] + ls[2][c] + ls[3][c];
        q = lq[0][c] + lq[1][c] + lq[2][c] + lq[3][c];
        atomicAdd(&stats[c], s);
        atomicAdd(&stats[64 + c], q);
    }
}

__global__ void k_finalize(const float* stats_in, const float* __restrict__ g,
                           const float* __restrict__ beta, float* as_out) {
    int c = threadIdx.x;
    float mu = stats_in[c] * (1.f / N_NODES);
    float var = stats_in[64 + c] * (1.f / N_NODES) - mu * mu;
    var = fmaxf(var, 0.f);
    float a = g[c] * rsqrtf(var + BN_EPS);
    as_out[c] = a;
    as_out[64 + c] = beta[c] - mu * a;
}

// MFMA apply1: v = relu(BN1(h1)) (stored to h1n f32), h2root = b2 + v @ root2 (aliases h1).
__global__ void k_apply1(const float* h1, const float* __restrict__ as1,
                         const uint4v* __restrict__ Bt, const float* __restrict__ b2,
                         float* __restrict__ h1n, float* h2) {
    int lane = threadIdx.x & 63;
    int m = lane & 15, kg = lane >> 4, orow4 = (lane >> 4) * 4;
    int tile = blockIdx.x * 4 + (threadIdx.x >> 6);
    int nb = tile * 16;
    if (nb >= N_NODES) return;
    int node = nb + m;
    const float* hr = h1 + (size_t)node * HDIM;

    float4 a0 = *(const float4*)(as1 + kg * 8), a1 = *(const float4*)(as1 + kg * 8 + 4);
    float4 s0 = *(const float4*)(as1 + 64 + kg * 8), s1 = *(const float4*)(as1 + 64 + kg * 8 + 4);
    float4 a2 = *(const float4*)(as1 + 32 + kg * 8), a3 = *(const float4*)(as1 + 32 + kg * 8 + 4);
    float4 s2 = *(const float4*)(as1 + 96 + kg * 8), s3 = *(const float4*)(as1 + 96 + kg * 8 + 4);

    float4 v0 = *(const float4*)(hr + kg * 8), v1 = *(const float4*)(hr + kg * 8 + 4);
    float4 v2 = *(const float4*)(hr + 32 + kg * 8), v3 = *(const float4*)(hr + 32 + kg * 8 + 4);

    float r0[8], r1[8];
#pragma unroll
    for (int p = 0; p < 4; ++p) {
        r0[p]     = fmaxf(fmaf((&v0.x)[p], (&a0.x)[p], (&s0.x)[p]), 0.f);
        r0[p + 4] = fmaxf(fmaf((&v1.x)[p], (&a1.x)[p], (&s1.x)[p]), 0.f);
        r1[p]     = fmaxf(fmaf((&v2.x)[p], (&a2.x)[p], (&s2.x)[p]), 0.f);
        r1[p + 4] = fmaxf(fmaf((&v3.x)[p], (&a3.x)[p], (&s3.x)[p]), 0.f);
    }
    *(float4*)(h1n + (size_t)node * HDIM + kg * 8)     = float4{r0[0], r0[1], r0[2], r0[3]};
    *(float4*)(h1n + (size_t)node * HDIM + kg * 8 + 4) = float4{r0[4], r0[5], r0[6], r0[7]};
    *(float4*)(h1n + (size_t)node * HDIM + 32 + kg * 8)     = float4{r1[0], r1[1], r1[2], r1[3]};
    *(float4*)(h1n + (size_t)node * HDIM + 32 + kg * 8 + 4) = float4{r1[4], r1[5], r1[6], r1[7]};

    bfrag A0 = __builtin_bit_cast(bfrag, uint4v{pk2bf(r0[0], r0[1]), pk2bf(r0[2], r0[3]),
                                                pk2bf(r0[4], r0[5]), pk2bf(r0[6], r0[7])});
    bfrag A1 = __builtin_bit_cast(bfrag, uint4v{pk2bf(r1[0], r1[1]), pk2bf(r1[2], r1[3]),
                                                pk2bf(r1[4], r1[5]), pk2bf(r1[6], r1[7])});

    const facc zero4 = {0.f, 0.f, 0.f, 0.f};
#pragma unroll
    for (int ot = 0; ot < 4; ++ot) {
        bfrag B0 = __builtin_bit_cast(bfrag, Bt[(ot * 2 + 0) * 64 + lane]);
        bfrag B1 = __builtin_bit_cast(bfrag, Bt[(ot * 2 + 1) * 64 + lane]);
        facc d = __builtin_amdgcn_mfma_f32_16x16x32_bf16(A0, B0, zero4, 0, 0, 0);
        d = __builtin_amdgcn_mfma_f32_16x16x32_bf16(A1, B1, d, 0, 0, 0);
        float bv = b2[ot * 16 + m];
#pragma unroll
        for (int j = 0; j < 4; ++j)
            h2[(size_t)(nb + orow4 + j) * HDIM + ot * 16 + m] = d[j] + bv;
    }
}

// out[n] = sigmoid( sum_c relu(BN2(h2[n][c])) * Wfc[c] + bfc )
__global__ void k_final(const float* __restrict__ h2, const float* __restrict__ as2,
                        const float* __restrict__ Wfc, const float* __restrict__ bfc,
                        float* __restrict__ out) {
    int lane = threadIdx.x & 63;
    int n = blockIdx.x * (blockDim.x >> 6) + (threadIdx.x >> 6);
    if (n >= N_NODES) return;
    float a = as2[lane], s = as2[64 + lane];
    float v = fmaxf(fmaf(h2[n * HDIM + lane], a, s), 0.f) * Wfc[lane];
#pragma unroll
    for (int off = 32; off > 0; off >>= 1) v += __shfl_xor(v, off, 64);
    if (lane == 0) out[n] = 1.f / (1.f + expf(-(v + bfc[0])));
}

extern "C" void kernel_launch(void* const* d_in, const int* in_sizes, int n_in,
                              void* d_out, int out_size, void* d_ws, size_t ws_size,
                              hipStream_t stream) {
    const float* x     = (const float*)d_in[0];
    const float* ea    = (const float*)d_in[1];
    const float* We1   = (const float*)d_in[2];
    const float* be1   = (const float*)d_in[3];
    const float* root1 = (const float*)d_in[4];
    const float* b1    = (const float*)d_in[5];
    const float* g1    = (const float*)d_in[6];
    const float* beta1 = (const float*)d_in[7];
    const float* We2   = (const float*)d_in[8];
    const float* be2   = (const float*)d_in[9];
    const float* root2 = (const float*)d_in[10];
    const float* b2    = (const float*)d_in[11];
    const float* g2    = (const float*)d_in[12];
    const float* beta2 = (const float*)d_in[13];
    const float* Wfc   = (const float*)d_in[14];
    const float* bfc   = (const float*)d_in[15];
    const int*   eidx  = (const int*)d_in[16];
    float* out = (float*)d_out;

    char* ws = (char*)d_ws;
    const size_t nbuf  = (size_t)N_NODES * HDIM * sizeof(float);   // 12.8MB
    const size_t msgsz = (size_t)N_EDGES * HDIM * sizeof(float);   // 25.6MB
    float* h1    = (float*)ws;                       // root term / reduced h / h2
    float* h1n   = (float*)(ws + nbuf);              // relu(BN1(h1))
    float* msg   = (float*)(ws + 2 * nbuf);          // [E][64] dense messages
    char*  meta  = ws + 2 * nbuf + msgsz;
    float* stats = (float*)meta;                                   // 512 f
    uint4v* Bt2  = (uint4v*)(meta + 2048);                         // 8KB
    uint4v* Bt1  = (uint4v*)(meta + 2048 + 8192);                  // 4KB
    int* cnt     = (int*)(meta + 16384);                           // 50k
    int* cursor  = cnt + N_NODES;                                  // 50k
    int* base    = cursor + N_NODES;                               // 50k+1
    int* csr     = base + N_NODES + 1;                             // 100k

    hipMemsetAsync(stats, 0, 512 * sizeof(float), stream);
    hipMemsetAsync(cnt, 0, N_NODES * sizeof(int), stream);

    const int eThreads = (N_EDGES + 255) / 256;   // 391
    k_count<<<eThreads, 256, 0, stream>>>(eidx, cnt);
    k_scan<<<1, 1024, 0, stream>>>(cnt, base, cursor);
    k_scatter<<<eThreads, 256, 0, stream>>>(eidx, cursor, csr);
    k_packB<HDIM><<<1, 256, 0, stream>>>(root2, Bt2);
    k_packB<FNODE><<<1, 256, 0, stream>>>(root1, Bt1);

    const int edgeBlocks = 2 * ((N_EDGES / 16 + 3) / 4);  // 3126
    const int nodeBlocks = (N_NODES + 3) / 4;             // 12500
    const int tileBlocks = (N_NODES / 16 + 3) / 4;        // 782

    k_node1<<<tileBlocks, 256, 0, stream>>>(x, Bt1, b1, h1);
    k_edge<FNODE, 2><<<edgeBlocks, 256, 0, stream>>>(x, ea, We1, be1, eidx, msg);
    k_reduce<<<nodeBlocks, 256, 0, stream>>>(h1, msg, base, csr, h1);
    k_stats<<<256, 256, 0, stream>>>(h1, stats);
    k_finalize<<<1, 64, 0, stream>>>(stats, g1, beta1, stats + 128);
    k_apply1<<<tileBlocks, 256, 0, stream>>>(h1, stats + 128, Bt2, b2, h1n, h1);
    k_edge<HDIM, 4><<<edgeBlocks, 256, 0, stream>>>(h1n, ea, We2, be2, eidx, msg);
    k_reduce<<<nodeBlocks, 256, 0, stream>>>(h1, msg, base, csr, h1);
    k_stats<<<256, 256, 0, stream>>>(h1, stats + 256);
    k_finalize<<<1, 64, 0, stream>>>(stats + 256, g2, beta2, stats + 384);
    k_final<<<nodeBlocks, 256, 0, stream>>>(h1, stats + 384, Wfc, bfc, out);
}

// Round 15
// 210.469 us; speedup vs baseline: 1.4840x; 1.4840x over previous
//
#include <hip/hip_runtime.h>
#include <math.h>

#define N_NODES 50000
#define N_EDGES 100000
#define FNODE 22
#define HDIM 64
#define BN_EPS 1e-5f

typedef __attribute__((ext_vector_type(8))) short bfrag;   // 8 bf16 = A/B operand
typedef __attribute__((ext_vector_type(4))) float facc;    // 4 f32  = C/D
typedef __attribute__((ext_vector_type(4))) unsigned int uint4v;
typedef __attribute__((ext_vector_type(2))) unsigned int uint2v;

__device__ __forceinline__ unsigned f2bf(float x) {  // RNE f32->bf16
    unsigned u = __float_as_uint(x);
    return (u + 0x7FFFu + ((u >> 16) & 1u)) >> 16;
}
__device__ __forceinline__ unsigned pk2bf(float lo, float hi) {
    return f2bf(lo) | (f2bf(hi) << 16);
}
__device__ __forceinline__ float bflo(unsigned w) { return __uint_as_float(w << 16); }
__device__ __forceinline__ float bfhi(unsigned w) { return __uint_as_float(w & 0xFFFF0000u); }

// ---------- CSR-by-dst build (parallel scan; int atomics only) ----------
__global__ void k_count(const int* __restrict__ eidx, int* __restrict__ cnt) {
    int e = blockIdx.x * 256 + threadIdx.x;
    if (e < N_EDGES) atomicAdd(&cnt[eidx[N_EDGES + e]], 1);
}

__global__ void k_scanA(const int* __restrict__ cnt, int* __restrict__ excl,
                        int* __restrict__ bsum) {
    __shared__ int sh[256];
    int g = blockIdx.x * 256 + threadIdx.x;
    int c = (g < N_NODES) ? cnt[g] : 0;
    sh[threadIdx.x] = c;
    __syncthreads();
    for (int off = 1; off < 256; off <<= 1) {
        int v = sh[threadIdx.x];
        int u = (threadIdx.x >= off) ? sh[threadIdx.x - off] : 0;
        __syncthreads();
        sh[threadIdx.x] = v + u;
        __syncthreads();
    }
    if (g < N_NODES) excl[g] = sh[threadIdx.x] - c;
    if (threadIdx.x == 255) bsum[blockIdx.x] = sh[255];
}

__global__ void k_scanB(const int* __restrict__ bsum, int* __restrict__ bbase, int nb) {
    __shared__ int sh[256];
    int t = threadIdx.x;
    int v = (t < nb) ? bsum[t] : 0;
    sh[t] = v;
    __syncthreads();
    for (int off = 1; off < 256; off <<= 1) {
        int a = sh[t];
        int u = (t >= off) ? sh[t - off] : 0;
        __syncthreads();
        sh[t] = a + u;
        __syncthreads();
    }
    if (t < nb) bbase[t] = sh[t] - v;
}

__global__ void k_scanC(const int* __restrict__ excl, const int* __restrict__ bbase,
                        int* __restrict__ cursor) {
    int g = blockIdx.x * 256 + threadIdx.x;
    if (g < N_NODES) cursor[g] = excl[g] + bbase[blockIdx.x];
}

// scatter edges into dst-sorted order; pre-pack ea as bf16 A-fragment halves
__global__ void k_scatter(const int* __restrict__ eidx, const float* __restrict__ ea,
                          int* __restrict__ cursor, int* __restrict__ srcsort,
                          int* __restrict__ dstsort, uint2v* __restrict__ easort) {
    int e = blockIdx.x * 256 + threadIdx.x;
    if (e < N_EDGES) {
        int d = eidx[N_EDGES + e];
        int p = atomicAdd(&cursor[d], 1);
        srcsort[p] = eidx[e];
        dstsort[p] = d;
        float4 v = ((const float4*)ea)[e];
        easort[p] = uint2v{pk2bf(v.x, v.y), pk2bf(v.z, v.w)};
    }
}

// pack x -> bf16 rows of 24 (48B, L2-resident)
__global__ void k_packX(const float* __restrict__ x, unsigned* __restrict__ xbf) {
    int idx = blockIdx.x * 256 + threadIdx.x;
    if (idx < N_NODES * 12) {
        int n = idx / 12, c2 = idx - n * 12;
        int c = c2 * 2;
        float lo = (c < FNODE) ? x[n * FNODE + c] : 0.f;
        float hi = (c + 1 < FNODE) ? x[n * FNODE + c + 1] : 0.f;
        xbf[idx] = pk2bf(lo, hi);
    }
}

// ---------- weight packing for node GEMMs ----------
template <int K>
__global__ void k_packB(const float* __restrict__ W, uint4v* __restrict__ Bt) {
    constexpr int NQ = (K + 31) / 32;
    int t = threadIdx.x;
    int ot = t >> 6, lane = t & 63;
    int o = ot * 16 + (lane & 15);
    int kg = lane >> 4;
#pragma unroll
    for (int q = 0; q < NQ; ++q) {
        unsigned w[4];
#pragma unroll
        for (int p = 0; p < 4; ++p) {
            int k0 = q * 32 + kg * 8 + 2 * p;
            float lo = (k0 < K) ? W[k0 * HDIM + o] : 0.f;
            float hi = (k0 + 1 < K) ? W[(k0 + 1) * HDIM + o] : 0.f;
            w[p] = pk2bf(lo, hi);
        }
        Bt[(ot * NQ + q) * 64 + lane] = uint4v{w[0], w[1], w[2], w[3]};
    }
}

// MFMA node1: h1 = b1 + x @ root1
__global__ void k_node1(const float* __restrict__ x, const uint4v* __restrict__ Bt1,
                        const float* __restrict__ b1, float* __restrict__ h1) {
    int lane = threadIdx.x & 63;
    int m = lane & 15, kg = lane >> 4, orow4 = kg * 4;
    int tile = blockIdx.x * 4 + (threadIdx.x >> 6);
    int nb = tile * 16;
    if (nb >= N_NODES) return;
    const float* xr = x + (size_t)(nb + m) * FNODE;
    float xv[8];
#pragma unroll
    for (int p = 0; p < 4; ++p) {
        int c = kg * 8 + 2 * p;
        float2 v = (c + 1 < FNODE) ? *(const float2*)(xr + c) : float2{0.f, 0.f};
        xv[2 * p] = v.x; xv[2 * p + 1] = v.y;
    }
    bfrag A = __builtin_bit_cast(bfrag, uint4v{pk2bf(xv[0], xv[1]), pk2bf(xv[2], xv[3]),
                                               pk2bf(xv[4], xv[5]), pk2bf(xv[6], xv[7])});
    const facc zero4 = {0.f, 0.f, 0.f, 0.f};
#pragma unroll
    for (int ot = 0; ot < 4; ++ot) {
        bfrag B = __builtin_bit_cast(bfrag, Bt1[ot * 64 + lane]);
        facc d = __builtin_amdgcn_mfma_f32_16x16x32_bf16(A, B, zero4, 0, 0, 0);
        float bv = b1[ot * 16 + m];
#pragma unroll
        for (int j = 0; j < 4; ++j)
            h1[(size_t)(nb + orow4 + j) * HDIM + ot * 16 + m] = d[j] + bv;
    }
}

// MFMA edge kernel v11: dst-sorted slots + fused in-wave reduction.
//  - waves process 16 dst-contiguous edge slots; easort/srcsort/dstsort read sequentially
//  - h rows gathered as bf16 (half the bytes of R13)
//  - per-dst runs summed through a per-wave LDS slab; wave-contained runs -> plain RMW
//    (sole writer; o-halves line-disjoint), boundary runs -> atomicAdd (<=2/wave)
//  - inner compute identical to R13 (i-pair LDS weights, bias via MFMA C operand)
// ROWB = bytes per h row (conv1: 48 bf16-packed x, conv2: 128 bf16 h)
template <int IN, int CHUNK, int ROWB>
__launch_bounds__(256, 4)
__global__ void k_edge(const char* __restrict__ hrows, const uint2v* __restrict__ easort,
                       const int* __restrict__ srcsort, const int* __restrict__ dstsort,
                       const float* __restrict__ We, const float* __restrict__ be,
                       float* __restrict__ out) {
    constexpr int INH = IN * HDIM;
    constexpr int IP = IN / 2;
    __shared__ uint4v Wd[IP * 32];
    __shared__ unsigned Bp[IP * 32];
    __shared__ float slab[4][16 * 33];

    int obeg = (blockIdx.x & 1) * 32;
    int tileblk = blockIdx.x >> 1;

    for (int idx = threadIdx.x; idx < IP * 32; idx += 256) {
        int ip = idx >> 5, oloc = idx & 31;
        int c0 = (2 * ip) * HDIM + obeg + oloc;
        int c1 = c0 + HDIM;
        Wd[idx] = uint4v{pk2bf(We[c0], We[INH + c0]),
                         pk2bf(We[2 * INH + c0], We[3 * INH + c0]),
                         pk2bf(We[c1], We[INH + c1]),
                         pk2bf(We[2 * INH + c1], We[3 * INH + c1])};
        Bp[idx] = pk2bf(be[c0], be[c1]);
    }
    __syncthreads();

    int lane = threadIdx.x & 63;
    int e16 = lane & 15;
    int orow4 = (lane >> 4) * 4;
    int tile = tileblk * 4 + (threadIdx.x >> 6);
    int s = tile * 16;                    // first sorted slot of this wave
    if (s >= N_EDGES) return;
    float* sl = &slab[threadIdx.x >> 6][0];

    bool act = lane < 16;
    uint2v eav = easort[s + e16];
    bfrag A0 = __builtin_bit_cast(bfrag, uint4v{act ? eav.x : 0u, act ? eav.y : 0u, 0u, 0u});

    unsigned offA[4];
#pragma unroll
    for (int j = 0; j < 4; ++j)
        offA[j] = (unsigned)srcsort[s + orow4 + j] * ROWB;

    const facc zero4 = {0.f, 0.f, 0.f, 0.f};
    facc m0[2] = {zero4, zero4};

#pragma unroll
    for (int i0 = 0; i0 < IN; i0 += CHUNK) {
        float cA[4][CHUNK];
#pragma unroll
        for (int j = 0; j < 4; ++j) {
            if constexpr (CHUNK == 4) {
                uint2v hv = *(const uint2v*)(hrows + offA[j] + (size_t)i0 * 2);
                cA[j][0] = bflo(hv.x); cA[j][1] = bfhi(hv.x);
                cA[j][2] = bflo(hv.y); cA[j][3] = bfhi(hv.y);
            } else {
                unsigned hv = *(const unsigned*)(hrows + offA[j] + (size_t)i0 * 2);
                cA[j][0] = bflo(hv); cA[j][1] = bfhi(hv);
            }
        }
#pragma unroll
        for (int t = 0; t < 2; ++t) {
#pragma unroll
            for (int d2 = 0; d2 < CHUNK / 2; ++d2) {
                int ip = i0 / 2 + d2;
                uint4v wq = Wd[ip * 32 + t * 16 + e16];
                unsigned bq = Bp[ip * 32 + t * 16 + e16];
                float bl = bflo(bq), bh = bfhi(bq);
                facc cl = {bl, bl, bl, bl};
                facc ch = {bh, bh, bh, bh};
                bfrag Blo = __builtin_bit_cast(bfrag, uint4v{wq.x, wq.y, 0u, 0u});
                bfrag Bhi = __builtin_bit_cast(bfrag, uint4v{wq.z, wq.w, 0u, 0u});
                facc t0 = __builtin_amdgcn_mfma_f32_16x16x32_bf16(A0, Blo, cl, 0, 0, 0);
#pragma unroll
                for (int j = 0; j < 4; ++j)
                    m0[t][j] = fmaf(cA[j][2 * d2], fmaxf(t0[j], 0.f), m0[t][j]);
                t0 = __builtin_amdgcn_mfma_f32_16x16x32_bf16(A0, Bhi, ch, 0, 0, 0);
#pragma unroll
                for (int j = 0; j < 4; ++j)
                    m0[t][j] = fmaf(cA[j][2 * d2 + 1], fmaxf(t0[j], 0.f), m0[t][j]);
            }
        }
    }

    // stash fragments: slab[slot][o32]
#pragma unroll
    for (int t = 0; t < 2; ++t)
#pragma unroll
        for (int j = 0; j < 4; ++j)
            sl[(orow4 + j) * 33 + t * 16 + e16] = m0[t][j];

    // fused per-dst reduction over this wave's 16 slots (branches are wave-uniform)
    int dprev = (s > 0) ? dstsort[s - 1] : -1;
    int dnext = (s + 16 < N_EDGES) ? dstsort[s + 16] : -1;
    int col = lane & 31;
    bool wlo = lane < 32;
    float acc = 0.f;
    int dcur = dstsort[s];
    int runstart = 0;
    for (int k = 0; k < 16; ++k) {
        acc += sl[k * 33 + col];
        bool isLast = (k == 15);
        int dn = isLast ? -2 : dstsort[s + k + 1];
        if (isLast || dn != dcur) {
            bool unsafe = (runstart == 0 && dcur == dprev) || (isLast && dcur == dnext);
            if (wlo) {
                size_t idx = (size_t)dcur * HDIM + obeg + col;
                if (unsafe) atomicAdd(&out[idx], acc);
                else        out[idx] += acc;          // sole writer: plain RMW
            }
            acc = 0.f;
            dcur = dn;
            runstart = k + 1;
        }
    }
}

// Per-channel sum & sumsq over N rows -> stats[0:64]=sum, stats[64:128]=sumsq (pre-zeroed)
__global__ void k_stats(const float* __restrict__ hbuf, float* stats) {
    int c = threadIdx.x & 63;
    int r = threadIdx.x >> 6;
    int rowsPer = blockDim.x >> 6;
    float s = 0.f, q = 0.f;
    for (int n = blockIdx.x * rowsPer + r; n < N_NODES; n += gridDim.x * rowsPer) {
        float v = hbuf[n * HDIM + c];
        s += v;
        q = fmaf(v, v, q);
    }
    __shared__ float ls[4][64], lq[4][64];
    ls[r][c] = s;
    lq[r][c] = q;
    __syncthreads();
    if (r == 0) {
        s = ls[0][c] + ls[1][c] + ls[2][c] + ls[3][c];
        q = lq[0][c] + lq[1][c] + lq[2][c] + lq[3][c];
        atomicAdd(&stats[c], s);
        atomicAdd(&stats[64 + c], q);
    }
}

__global__ void k_finalize(const float* stats_in, const float* __restrict__ g,
                           const float* __restrict__ beta, float* as_out) {
    int c = threadIdx.x;
    float mu = stats_in[c] * (1.f / N_NODES);
    float var = stats_in[64 + c] * (1.f / N_NODES) - mu * mu;
    var = fmaxf(var, 0.f);
    float a = g[c] * rsqrtf(var + BN_EPS);
    as_out[c] = a;
    as_out[64 + c] = beta[c] - mu * a;
}

// MFMA apply1: v = relu(BN1(h1)); store v as bf16 rows (conv2 gather) and
// h2root = b2 + v @ root2 into h2 (aliases h1; wave reads its rows first).
__global__ void k_apply1(const float* h1, const float* __restrict__ as1,
                         const uint4v* __restrict__ Bt, const float* __restrict__ b2,
                         unsigned* __restrict__ hbf, float* h2) {
    int lane = threadIdx.x & 63;
    int m = lane & 15, kg = lane >> 4, orow4 = (lane >> 4) * 4;
    int tile = blockIdx.x * 4 + (threadIdx.x >> 6);
    int nb = tile * 16;
    if (nb >= N_NODES) return;
    int node = nb + m;
    const float* hr = h1 + (size_t)node * HDIM;

    float4 a0 = *(const float4*)(as1 + kg * 8), a1 = *(const float4*)(as1 + kg * 8 + 4);
    float4 s0 = *(const float4*)(as1 + 64 + kg * 8), s1 = *(const float4*)(as1 + 64 + kg * 8 + 4);
    float4 a2 = *(const float4*)(as1 + 32 + kg * 8), a3 = *(const float4*)(as1 + 32 + kg * 8 + 4);
    float4 s2 = *(const float4*)(as1 + 96 + kg * 8), s3 = *(const float4*)(as1 + 96 + kg * 8 + 4);

    float4 v0 = *(const float4*)(hr + kg * 8), v1 = *(const float4*)(hr + kg * 8 + 4);
    float4 v2 = *(const float4*)(hr + 32 + kg * 8), v3 = *(const float4*)(hr + 32 + kg * 8 + 4);

    float r0[8], r1[8];
#pragma unroll
    for (int p = 0; p < 4; ++p) {
        r0[p]     = fmaxf(fmaf((&v0.x)[p], (&a0.x)[p], (&s0.x)[p]), 0.f);
        r0[p + 4] = fmaxf(fmaf((&v1.x)[p], (&a1.x)[p], (&s1.x)[p]), 0.f);
        r1[p]     = fmaxf(fmaf((&v2.x)[p], (&a2.x)[p], (&s2.x)[p]), 0.f);
        r1[p + 4] = fmaxf(fmaf((&v3.x)[p], (&a3.x)[p], (&s3.x)[p]), 0.f);
    }
    uint4v pk0 = uint4v{pk2bf(r0[0], r0[1]), pk2bf(r0[2], r0[3]),
                        pk2bf(r0[4], r0[5]), pk2bf(r0[6], r0[7])};
    uint4v pk1 = uint4v{pk2bf(r1[0], r1[1]), pk2bf(r1[2], r1[3]),
                        pk2bf(r1[4], r1[5]), pk2bf(r1[6], r1[7])};
    // bf16 row: 32 dwords per node; this lane covers dwords kg*4.. and 16+kg*4..
    *(uint4v*)(hbf + (size_t)node * 32 + kg * 4)      = pk0;
    *(uint4v*)(hbf + (size_t)node * 32 + 16 + kg * 4) = pk1;

    bfrag A0 = __builtin_bit_cast(bfrag, pk0);
    bfrag A1 = __builtin_bit_cast(bfrag, pk1);

    const facc zero4 = {0.f, 0.f, 0.f, 0.f};
#pragma unroll
    for (int ot = 0; ot < 4; ++ot) {
        bfrag B0 = __builtin_bit_cast(bfrag, Bt[(ot * 2 + 0) * 64 + lane]);
        bfrag B1 = __builtin_bit_cast(bfrag, Bt[(ot * 2 + 1) * 64 + lane]);
        facc d = __builtin_amdgcn_mfma_f32_16x16x32_bf16(A0, B0, zero4, 0, 0, 0);
        d = __builtin_amdgcn_mfma_f32_16x16x32_bf16(A1, B1, d, 0, 0, 0);
        float bv = b2[ot * 16 + m];
#pragma unroll
        for (int j = 0; j < 4; ++j)
            h2[(size_t)(nb + orow4 + j) * HDIM + ot * 16 + m] = d[j] + bv;
    }
}

// out[n] = sigmoid( sum_c relu(BN2(h2[n][c])) * Wfc[c] + bfc )
__global__ void k_final(const float* __restrict__ h2, const float* __restrict__ as2,
                        const float* __restrict__ Wfc, const float* __restrict__ bfc,
                        float* __restrict__ out) {
    int lane = threadIdx.x & 63;
    int n = blockIdx.x * (blockDim.x >> 6) + (threadIdx.x >> 6);
    if (n >= N_NODES) return;
    float a = as2[lane], s = as2[64 + lane];
    float v = fmaxf(fmaf(h2[n * HDIM + lane], a, s), 0.f) * Wfc[lane];
#pragma unroll
    for (int off = 32; off > 0; off >>= 1) v += __shfl_xor(v, off, 64);
    if (lane == 0) out[n] = 1.f / (1.f + expf(-(v + bfc[0])));
}

extern "C" void kernel_launch(void* const* d_in, const int* in_sizes, int n_in,
                              void* d_out, int out_size, void* d_ws, size_t ws_size,
                              hipStream_t stream) {
    const float* x     = (const float*)d_in[0];
    const float* ea    = (const float*)d_in[1];
    const float* We1   = (const float*)d_in[2];
    const float* be1   = (const float*)d_in[3];
    const float* root1 = (const float*)d_in[4];
    const float* b1    = (const float*)d_in[5];
    const float* g1    = (const float*)d_in[6];
    const float* beta1 = (const float*)d_in[7];
    const float* We2   = (const float*)d_in[8];
    const float* be2   = (const float*)d_in[9];
    const float* root2 = (const float*)d_in[10];
    const float* b2    = (const float*)d_in[11];
    const float* g2    = (const float*)d_in[12];
    const float* beta2 = (const float*)d_in[13];
    const float* Wfc   = (const float*)d_in[14];
    const float* bfc   = (const float*)d_in[15];
    const int*   eidx  = (const int*)d_in[16];
    float* out = (float*)d_out;

    char* ws = (char*)d_ws;
    size_t off = 0;
    auto alloc = [&](size_t bytes) { char* p = ws + off; off = (off + bytes + 255) & ~(size_t)255; return p; };
    float*    h1      = (float*)alloc((size_t)N_NODES * HDIM * 4);   // root/h/h2
    unsigned* hbf     = (unsigned*)alloc((size_t)N_NODES * 32 * 4);  // bf16 h rows
    unsigned* xbf     = (unsigned*)alloc((size_t)N_NODES * 12 * 4);  // bf16 x rows (pad 24)
    uint2v*   easort  = (uint2v*)alloc((size_t)N_EDGES * 8);
    int*      srcsort = (int*)alloc((size_t)N_EDGES * 4);
    int*      dstsort = (int*)alloc((size_t)N_EDGES * 4);
    int*      cnt     = (int*)alloc((size_t)N_NODES * 4);
    int*      cursor  = (int*)alloc((size_t)N_NODES * 4);
    int*      excl    = (int*)alloc((size_t)N_NODES * 4);
    int*      bsum    = (int*)alloc(256 * 4);
    int*      bbase   = (int*)alloc(256 * 4);
    float*    stats   = (float*)alloc(512 * 4);
    uint4v*   Bt2     = (uint4v*)alloc(8 * 64 * 16);
    uint4v*   Bt1     = (uint4v*)alloc(4 * 64 * 16);

    hipMemsetAsync(stats, 0, 512 * sizeof(float), stream);
    hipMemsetAsync(cnt, 0, N_NODES * sizeof(int), stream);

    const int eBlocks = (N_EDGES + 255) / 256;        // 391
    const int nScanBlocks = (N_NODES + 255) / 256;    // 196
    k_count<<<eBlocks, 256, 0, stream>>>(eidx, cnt);
    k_scanA<<<nScanBlocks, 256, 0, stream>>>(cnt, excl, bsum);
    k_scanB<<<1, 256, 0, stream>>>(bsum, bbase, nScanBlocks);
    k_scanC<<<nScanBlocks, 256, 0, stream>>>(excl, bbase, cursor);
    k_scatter<<<eBlocks, 256, 0, stream>>>(eidx, ea, cursor, srcsort, dstsort, easort);
    k_packX<<<(N_NODES * 12 + 255) / 256, 256, 0, stream>>>(x, xbf);
    k_packB<HDIM><<<1, 256, 0, stream>>>(root2, Bt2);
    k_packB<FNODE><<<1, 256, 0, stream>>>(root1, Bt1);

    const int edgeBlocks = 2 * ((N_EDGES / 16 + 3) / 4);  // 3126: 16-slot waves, o-half pairs
    const int nodeBlocks = (N_NODES + 3) / 4;
    const int tileBlocks = (N_NODES / 16 + 3) / 4;        // 782

    k_node1<<<tileBlocks, 256, 0, stream>>>(x, Bt1, b1, h1);
    k_edge<FNODE, 2, 48><<<edgeBlocks, 256, 0, stream>>>((const char*)xbf, easort, srcsort,
                                                         dstsort, We1, be1, h1);
    k_stats<<<256, 256, 0, stream>>>(h1, stats);
    k_finalize<<<1, 64, 0, stream>>>(stats, g1, beta1, stats + 128);
    k_apply1<<<tileBlocks, 256, 0, stream>>>(h1, stats + 128, Bt2, b2, hbf, h1);
    k_edge<HDIM, 4, 128><<<edgeBlocks, 256, 0, stream>>>((const char*)hbf, easort, srcsort,
                                                         dstsort, We2, be2, h1);
    k_stats<<<256, 256, 0, stream>>>(h1, stats + 256);
    k_finalize<<<1, 64, 0, stream>>>(stats + 256, g2, beta2, stats + 384);
    k_final<<<nodeBlocks, 256, 0, stream>>>(h1, stats + 384, Wfc, bfc, out);
}

// Round 16
// 165.810 us; speedup vs baseline: 1.8837x; 1.2693x over previous
//
#include <hip/hip_runtime.h>
#include <math.h>

#define N_NODES 50000
#define N_EDGES 100000
#define FNODE 22
#define HDIM 64
#define BN_EPS 1e-5f

typedef __attribute__((ext_vector_type(8))) short bfrag;   // 8 bf16 = A/B operand
typedef __attribute__((ext_vector_type(4))) float facc;    // 4 f32  = C/D
typedef __attribute__((ext_vector_type(4))) unsigned int uint4v;

__device__ __forceinline__ unsigned f2bf(float x) {  // RNE f32->bf16
    unsigned u = __float_as_uint(x);
    return (u + 0x7FFFu + ((u >> 16) & 1u)) >> 16;
}
__device__ __forceinline__ unsigned pk2bf(float lo, float hi) {
    return f2bf(lo) | (f2bf(hi) << 16);
}
__device__ __forceinline__ float bflo(unsigned w) { return __uint_as_float(w << 16); }
__device__ __forceinline__ float bfhi(unsigned w) { return __uint_as_float(w & 0xFFFF0000u); }

// pack x -> bf16 rows of 24 (48B; cols >= FNODE are zero)
__global__ void k_packX(const float* __restrict__ x, unsigned* __restrict__ xbf) {
    int idx = blockIdx.x * 256 + threadIdx.x;
    if (idx < N_NODES * 12) {
        int n = idx / 12, c2 = idx - n * 12;
        int c = c2 * 2;
        float lo = (c < FNODE) ? x[n * FNODE + c] : 0.f;
        float hi = (c + 1 < FNODE) ? x[n * FNODE + c + 1] : 0.f;
        xbf[idx] = pk2bf(lo, hi);
    }
}

// Pack a [K][64] weight matrix into MFMA B-fragments (16x16x32, K zero-padded to 32*NQ).
template <int K>
__global__ void k_packB(const float* __restrict__ W, uint4v* __restrict__ Bt) {
    constexpr int NQ = (K + 31) / 32;
    int t = threadIdx.x;
    int ot = t >> 6, lane = t & 63;
    int o = ot * 16 + (lane & 15);
    int kg = lane >> 4;
#pragma unroll
    for (int q = 0; q < NQ; ++q) {
        unsigned w[4];
#pragma unroll
        for (int p = 0; p < 4; ++p) {
            int k0 = q * 32 + kg * 8 + 2 * p;
            float lo = (k0 < K) ? W[k0 * HDIM + o] : 0.f;
            float hi = (k0 + 1 < K) ? W[(k0 + 1) * HDIM + o] : 0.f;
            w[p] = pk2bf(lo, hi);
        }
        Bt[(ot * NQ + q) * 64 + lane] = uint4v{w[0], w[1], w[2], w[3]};
    }
}

// MFMA node1: h1 = b1 + x @ root1
__global__ void k_node1(const float* __restrict__ x, const uint4v* __restrict__ Bt1,
                        const float* __restrict__ b1, float* __restrict__ h1) {
    int lane = threadIdx.x & 63;
    int m = lane & 15, kg = lane >> 4, orow4 = kg * 4;
    int tile = blockIdx.x * 4 + (threadIdx.x >> 6);
    int nb = tile * 16;
    if (nb >= N_NODES) return;
    const float* xr = x + (size_t)(nb + m) * FNODE;
    float xv[8];
#pragma unroll
    for (int p = 0; p < 4; ++p) {
        int c = kg * 8 + 2 * p;
        float2 v = (c + 1 < FNODE) ? *(const float2*)(xr + c) : float2{0.f, 0.f};
        xv[2 * p] = v.x; xv[2 * p + 1] = v.y;
    }
    bfrag A = __builtin_bit_cast(bfrag, uint4v{pk2bf(xv[0], xv[1]), pk2bf(xv[2], xv[3]),
                                               pk2bf(xv[4], xv[5]), pk2bf(xv[6], xv[7])});
    const facc zero4 = {0.f, 0.f, 0.f, 0.f};
#pragma unroll
    for (int ot = 0; ot < 4; ++ot) {
        bfrag B = __builtin_bit_cast(bfrag, Bt1[ot * 64 + lane]);
        facc d = __builtin_amdgcn_mfma_f32_16x16x32_bf16(A, B, zero4, 0, 0, 0);
        float bv = b1[ot * 16 + m];
#pragma unroll
        for (int j = 0; j < 4; ++j)
            h1[(size_t)(nb + orow4 + j) * HDIM + ot * 16 + m] = d[j] + bv;
    }
}

// MFMA edge kernel v12: minimize VMEM instruction count (TA-bound hypothesis).
//  - 16 edges/wave, o-split block pairs; weights = pre-assembled B-fragments in LDS
//    {w01,w23,be,0} (R10-proven; bias in B, A carries 1.0 at k=4, lanes>=16 of A zero)
//  - h rows staged bf16->f32 into a wave-private LDS slab with 1-2 fully packed 1KB
//    global loads (64 lanes x 16B) instead of 64 broadcast gathers
//  - consume: 16-lane-broadcast ds_read_b128 from slab (2-way bank alias max)
//  - epilogue: R13 plain atomics (4 edges x 16 contiguous dwords, o-halves line-disjoint)
// ROWB = bf16 row bytes (conv1: 48, conv2: 128); SSTRIDE = slab stride in f32.
template <int IN, int ROWB, int SSTRIDE, int MINW>
__launch_bounds__(256, MINW)
__global__ void k_edge(const char* __restrict__ hrows, const float* __restrict__ ea,
                       const float* __restrict__ We, const float* __restrict__ be,
                       const int* __restrict__ eidx, float* __restrict__ out) {
    constexpr int INH = IN * HDIM;
    __shared__ uint4v Wf[IN * 32];            // [i*32+oloc] = {w01, w23, be, 0}
    __shared__ float hsl[4][16 * SSTRIDE];    // wave-private f32 h rows

    int obeg = (blockIdx.x & 1) * 32;
    int tileblk = blockIdx.x >> 1;

    for (int idx = threadIdx.x; idx < IN * 32; idx += 256) {
        int i = idx >> 5, oloc = idx & 31;
        int c = i * HDIM + obeg + oloc;
        Wf[idx] = uint4v{pk2bf(We[c], We[INH + c]),
                         pk2bf(We[2 * INH + c], We[3 * INH + c]),
                         f2bf(be[c]), 0u};
    }
    __syncthreads();

    int lane = threadIdx.x & 63;
    int e16 = lane & 15;
    int orow4 = (lane >> 4) * 4;
    int tile = tileblk * 4 + (threadIdx.x >> 6);
    int ebase = tile * 16;
    if (ebase >= N_EDGES) return;
    float* hs = &hsl[threadIdx.x >> 6][0];

    // A: lanes<16 carry k0..3 = ea, k4 = 1.0 (bias multiplier); lanes>=16 all zero
    bool act = lane < 16;
    float4 ea0 = ((const float4*)ea)[ebase + e16];
    unsigned aone = act ? 0x3F80u : 0u;
    bfrag A0 = __builtin_bit_cast(bfrag, uint4v{act ? pk2bf(ea0.x, ea0.y) : 0u,
                                                act ? pk2bf(ea0.z, ea0.w) : 0u, aone, 0u});

    // stage 16 h rows: bf16 global (16B/lane, fully packed) -> unpack -> f32 slab
    constexpr int SLOTS = 16 * (ROWB / 16);   // uint4 slots: conv2 128, conv1 48
    constexpr int SPR = ROWB / 16;            // slots per row
#pragma unroll
    for (int p = 0; p < (SLOTS + 63) / 64; ++p) {
        int idx = p * 64 + lane;
        if ((SLOTS % 64 == 0) || idx < SLOTS) {
            int r = idx / SPR, c16 = idx - r * SPR;
            int src = eidx[ebase + r];
            uint4v hv = *(const uint4v*)(hrows + (size_t)src * ROWB + c16 * 16);
            *(float4*)&hs[r * SSTRIDE + c16 * 8] =
                float4{bflo(hv.x), bfhi(hv.x), bflo(hv.y), bfhi(hv.y)};
            *(float4*)&hs[r * SSTRIDE + c16 * 8 + 4] =
                float4{bflo(hv.z), bfhi(hv.z), bflo(hv.w), bfhi(hv.w)};
        }
    }

    const facc zero4 = {0.f, 0.f, 0.f, 0.f};
    facc m0[2] = {zero4, zero4};

    constexpr int I4 = IN & ~3;
#pragma unroll
    for (int i0 = 0; i0 < I4; i0 += 4) {
        float4 hA[4];
#pragma unroll
        for (int j = 0; j < 4; ++j)
            hA[j] = *(const float4*)&hs[(orow4 + j) * SSTRIDE + i0];   // broadcast read
#pragma unroll
        for (int di = 0; di < 4; ++di) {
#pragma unroll
            for (int t = 0; t < 2; ++t) {
                bfrag B = __builtin_bit_cast(bfrag, Wf[(i0 + di) * 32 + t * 16 + e16]);
                facc t0 = __builtin_amdgcn_mfma_f32_16x16x32_bf16(A0, B, zero4, 0, 0, 0);
#pragma unroll
                for (int j = 0; j < 4; ++j)
                    m0[t][j] = fmaf((&hA[j].x)[di], fmaxf(t0[j], 0.f), m0[t][j]);
            }
        }
    }
    if constexpr ((IN & 3) != 0) {   // IN=22 tail: i = I4, I4+1 (slab cols >=IN are zero)
        float4 hA[4];
#pragma unroll
        for (int j = 0; j < 4; ++j)
            hA[j] = *(const float4*)&hs[(orow4 + j) * SSTRIDE + I4];
#pragma unroll
        for (int di = 0; di < (IN & 3); ++di) {
#pragma unroll
            for (int t = 0; t < 2; ++t) {
                bfrag B = __builtin_bit_cast(bfrag, Wf[(I4 + di) * 32 + t * 16 + e16]);
                facc t0 = __builtin_amdgcn_mfma_f32_16x16x32_bf16(A0, B, zero4, 0, 0, 0);
#pragma unroll
                for (int j = 0; j < 4; ++j)
                    m0[t][j] = fmaf((&hA[j].x)[di], fmaxf(t0[j], 0.f), m0[t][j]);
            }
        }
    }

    // epilogue: each atomic instr = 4 edges x 16 contiguous dwords (line-disjoint o-halves)
    int dA[4];
#pragma unroll
    for (int j = 0; j < 4; ++j)
        dA[j] = eidx[N_EDGES + ebase + orow4 + j];
#pragma unroll
    for (int t = 0; t < 2; ++t) {
#pragma unroll
        for (int j = 0; j < 4; ++j)
            atomicAdd(&out[(size_t)dA[j] * HDIM + obeg + t * 16 + e16], m0[t][j]);
    }
}

// Per-channel sum & sumsq over N rows -> stats[0:64]=sum, stats[64:128]=sumsq (pre-zeroed)
__global__ void k_stats(const float* __restrict__ hbuf, float* stats) {
    int c = threadIdx.x & 63;
    int r = threadIdx.x >> 6;
    int rowsPer = blockDim.x >> 6;
    float s = 0.f, q = 0.f;
    for (int n = blockIdx.x * rowsPer + r; n < N_NODES; n += gridDim.x * rowsPer) {
        float v = hbuf[n * HDIM + c];
        s += v;
        q = fmaf(v, v, q);
    }
    __shared__ float ls[4][64], lq[4][64];
    ls[r][c] = s;
    lq[r][c] = q;
    __syncthreads();
    if (r == 0) {
        s = ls[0][c] + ls[1][c] + ls[2][c] + ls[3][c];
        q = lq[0][c] + lq[1][c] + lq[2][c] + lq[3][c];
        atomicAdd(&stats[c], s);
        atomicAdd(&stats[64 + c], q);
    }
}

__global__ void k_finalize(const float* stats_in, const float* __restrict__ g,
                           const float* __restrict__ beta, float* as_out) {
    int c = threadIdx.x;
    float mu = stats_in[c] * (1.f / N_NODES);
    float var = stats_in[64 + c] * (1.f / N_NODES) - mu * mu;
    var = fmaxf(var, 0.f);
    float a = g[c] * rsqrtf(var + BN_EPS);
    as_out[c] = a;
    as_out[64 + c] = beta[c] - mu * a;
}

// MFMA apply1: v = relu(BN1(h1)); store v as bf16 rows (conv2 gather source) and
// h2root = b2 + v @ root2 into h2 (aliases h1; wave reads its rows first).
__global__ void k_apply1(const float* h1, const float* __restrict__ as1,
                         const uint4v* __restrict__ Bt, const float* __restrict__ b2,
                         unsigned* __restrict__ hbf, float* h2) {
    int lane = threadIdx.x & 63;
    int m = lane & 15, kg = lane >> 4, orow4 = (lane >> 4) * 4;
    int tile = blockIdx.x * 4 + (threadIdx.x >> 6);
    int nb = tile * 16;
    if (nb >= N_NODES) return;
    int node = nb + m;
    const float* hr = h1 + (size_t)node * HDIM;

    float4 a0 = *(const float4*)(as1 + kg * 8), a1 = *(const float4*)(as1 + kg * 8 + 4);
    float4 s0 = *(const float4*)(as1 + 64 + kg * 8), s1 = *(const float4*)(as1 + 64 + kg * 8 + 4);
    float4 a2 = *(const float4*)(as1 + 32 + kg * 8), a3 = *(const float4*)(as1 + 32 + kg * 8 + 4);
    float4 s2 = *(const float4*)(as1 + 96 + kg * 8), s3 = *(const float4*)(as1 + 96 + kg * 8 + 4);

    float4 v0 = *(const float4*)(hr + kg * 8), v1 = *(const float4*)(hr + kg * 8 + 4);
    float4 v2 = *(const float4*)(hr + 32 + kg * 8), v3 = *(const float4*)(hr + 32 + kg * 8 + 4);

    float r0[8], r1[8];
#pragma unroll
    for (int p = 0; p < 4; ++p) {
        r0[p]     = fmaxf(fmaf((&v0.x)[p], (&a0.x)[p], (&s0.x)[p]), 0.f);
        r0[p + 4] = fmaxf(fmaf((&v1.x)[p], (&a1.x)[p], (&s1.x)[p]), 0.f);
        r1[p]     = fmaxf(fmaf((&v2.x)[p], (&a2.x)[p], (&s2.x)[p]), 0.f);
        r1[p + 4] = fmaxf(fmaf((&v3.x)[p], (&a3.x)[p], (&s3.x)[p]), 0.f);
    }
    uint4v pk0 = uint4v{pk2bf(r0[0], r0[1]), pk2bf(r0[2], r0[3]),
                        pk2bf(r0[4], r0[5]), pk2bf(r0[6], r0[7])};
    uint4v pk1 = uint4v{pk2bf(r1[0], r1[1]), pk2bf(r1[2], r1[3]),
                        pk2bf(r1[4], r1[5]), pk2bf(r1[6], r1[7])};
    *(uint4v*)(hbf + (size_t)node * 32 + kg * 4)      = pk0;
    *(uint4v*)(hbf + (size_t)node * 32 + 16 + kg * 4) = pk1;

    bfrag A0 = __builtin_bit_cast(bfrag, pk0);
    bfrag A1 = __builtin_bit_cast(bfrag, pk1);

    const facc zero4 = {0.f, 0.f, 0.f, 0.f};
#pragma unroll
    for (int ot = 0; ot < 4; ++ot) {
        bfrag B0 = __builtin_bit_cast(bfrag, Bt[(ot * 2 + 0) * 64 + lane]);
        bfrag B1 = __builtin_bit_cast(bfrag, Bt[(ot * 2 + 1) * 64 + lane]);
        facc d = __builtin_amdgcn_mfma_f32_16x16x32_bf16(A0, B0, zero4, 0, 0, 0);
        d = __builtin_amdgcn_mfma_f32_16x16x32_bf16(A1, B1, d, 0, 0, 0);
        float bv = b2[ot * 16 + m];
#pragma unroll
        for (int j = 0; j < 4; ++j)
            h2[(size_t)(nb + orow4 + j) * HDIM + ot * 16 + m] = d[j] + bv;
    }
}

// out[n] = sigmoid( sum_c relu(BN2(h2[n][c])) * Wfc[c] + bfc )
__global__ void k_final(const float* __restrict__ h2, const float* __restrict__ as2,
                        const float* __restrict__ Wfc, const float* __restrict__ bfc,
                        float* __restrict__ out) {
    int lane = threadIdx.x & 63;
    int n = blockIdx.x * (blockDim.x >> 6) + (threadIdx.x >> 6);
    if (n >= N_NODES) return;
    float a = as2[lane], s = as2[64 + lane];
    float v = fmaxf(fmaf(h2[n * HDIM + lane], a, s), 0.f) * Wfc[lane];
#pragma unroll
    for (int off = 32; off > 0; off >>= 1) v += __shfl_xor(v, off, 64);
    if (lane == 0) out[n] = 1.f / (1.f + expf(-(v + bfc[0])));
}

extern "C" void kernel_launch(void* const* d_in, const int* in_sizes, int n_in,
                              void* d_out, int out_size, void* d_ws, size_t ws_size,
                              hipStream_t stream) {
    const float* x     = (const float*)d_in[0];
    const float* ea    = (const float*)d_in[1];
    const float* We1   = (const float*)d_in[2];
    const float* be1   = (const float*)d_in[3];
    const float* root1 = (const float*)d_in[4];
    const float* b1    = (const float*)d_in[5];
    const float* g1    = (const float*)d_in[6];
    const float* beta1 = (const float*)d_in[7];
    const float* We2   = (const float*)d_in[8];
    const float* be2   = (const float*)d_in[9];
    const float* root2 = (const float*)d_in[10];
    const float* b2    = (const float*)d_in[11];
    const float* g2    = (const float*)d_in[12];
    const float* beta2 = (const float*)d_in[13];
    const float* Wfc   = (const float*)d_in[14];
    const float* bfc   = (const float*)d_in[15];
    const int*   eidx  = (const int*)d_in[16];
    float* out = (float*)d_out;

    char* ws = (char*)d_ws;
    size_t off = 0;
    auto alloc = [&](size_t bytes) { char* p = ws + off; off = (off + bytes + 255) & ~(size_t)255; return p; };
    float*    h1    = (float*)alloc((size_t)N_NODES * HDIM * 4);   // root/h/h2
    unsigned* hbf   = (unsigned*)alloc((size_t)N_NODES * 32 * 4);  // bf16 h rows (128B)
    unsigned* xbf   = (unsigned*)alloc((size_t)N_NODES * 12 * 4);  // bf16 x rows (48B)
    float*    stats = (float*)alloc(512 * 4);
    uint4v*   Bt2   = (uint4v*)alloc(8 * 64 * 16);
    uint4v*   Bt1   = (uint4v*)alloc(4 * 64 * 16);

    hipMemsetAsync(stats, 0, 512 * sizeof(float), stream);
    k_packX<<<(N_NODES * 12 + 255) / 256, 256, 0, stream>>>(x, xbf);
    k_packB<HDIM><<<1, 256, 0, stream>>>(root2, Bt2);
    k_packB<FNODE><<<1, 256, 0, stream>>>(root1, Bt1);

    const int edgeBlocks = 2 * ((N_EDGES / 16 + 3) / 4);  // 3126: 16-edge waves, o-half pairs
    const int nodeBlocks = (N_NODES + 3) / 4;
    const int tileBlocks = (N_NODES / 16 + 3) / 4;        // 782

    k_node1<<<tileBlocks, 256, 0, stream>>>(x, Bt1, b1, h1);
    // conv1: ROWB=48 (bf16 x rows), slab stride 28 f32, 4 blocks/CU
    k_edge<FNODE, 48, 28, 4><<<edgeBlocks, 256, 0, stream>>>((const char*)xbf, ea,
                                                             We1, be1, eidx, h1);
    k_stats<<<256, 256, 0, stream>>>(h1, stats);
    k_finalize<<<1, 64, 0, stream>>>(stats, g1, beta1, stats + 128);
    k_apply1<<<tileBlocks, 256, 0, stream>>>(h1, stats + 128, Bt2, b2, hbf, h1);
    // conv2: ROWB=128 (bf16 h rows), slab stride 68 f32, 3 blocks/CU (50KB LDS)
    k_edge<HDIM, 128, 68, 3><<<edgeBlocks, 256, 0, stream>>>((const char*)hbf, ea,
                                                             We2, be2, eidx, h1);
    k_stats<<<256, 256, 0, stream>>>(h1, stats + 256);
    k_finalize<<<1, 64, 0, stream>>>(stats + 256, g2, beta2, stats + 384);
    k_final<<<nodeBlocks, 256, 0, stream>>>(h1, stats + 384, Wfc, bfc, out);
}